// Round 5
// baseline (259.118 us; speedup 1.0000x reference)
//
#include <hip/hip_runtime.h>
#include <cstdint>
#include <cstddef>

typedef float f32x4 __attribute__((ext_vector_type(4)));
typedef __bf16 bf16x8 __attribute__((ext_vector_type(8)));

#define BB 16
#define SEQ 1024
#define DMODEL 768
#define NHEAD 12
#define HDIM 64
#define MTOT (BB * SEQ)
#define NQKV (3 * DMODEL)
// 0.125 (hd^-0.5) * log2(e): QK^T then exp2 == exp(0.125 * qk)
#define QSCALE 0.18033688011112042f

static __device__ __forceinline__ unsigned short f2bf(float f) {
  unsigned int u = __builtin_bit_cast(unsigned int, f);
  u += 0x7fffu + ((u >> 16) & 1u);
  return (unsigned short)(u >> 16);
}

static __device__ __forceinline__ unsigned cvt_pk_bf16(float lo, float hi) {
  unsigned r;
  asm("v_cvt_pk_bf16_f32 %0, %1, %2" : "=v"(r) : "v"(lo), "v"(hi));
  return r;
}

static __device__ __forceinline__ void gload_lds16(const void* g, void* l) {
  __builtin_amdgcn_global_load_lds((__attribute__((address_space(1))) void*)g,
                                   (__attribute__((address_space(3))) void*)l,
                                   16, 0, 0);
}

// ---- prep: f32 -> bf16 convert (vectorized) ----
__global__ void k_cvt_bf16(const float4* __restrict__ in, ushort4* __restrict__ out, int n4) {
  int stride = gridDim.x * blockDim.x;
  for (int i = blockIdx.x * blockDim.x + threadIdx.x; i < n4; i += stride) {
    float4 v = in[i];
    ushort4 o;
    o.x = f2bf(v.x); o.y = f2bf(v.y); o.z = f2bf(v.z); o.w = f2bf(v.w);
    out[i] = o;
  }
}

// ---- prep: transpose f32 [R][C] -> bf16 [C][R] ----
__global__ void k_transpose_bf16(const float* __restrict__ in, unsigned short* __restrict__ out,
                                 int R, int C) {
  __shared__ float tile[32][33];
  int tx = threadIdx.x & 31, ty = threadIdx.x >> 5;
  int c0 = blockIdx.x * 32, r0 = blockIdx.y * 32;
#pragma unroll
  for (int i = 0; i < 4; ++i)
    tile[ty + i * 8][tx] = in[(size_t)(r0 + ty + i * 8) * C + c0 + tx];
  __syncthreads();
#pragma unroll
  for (int i = 0; i < 4; ++i)
    out[(size_t)(c0 + ty + i * 8) * R + r0 + tx] = f2bf(tile[tx][ty + i * 8]);
}

// ---- GEMM C[M,N] = A[M,K] * Bt[N,K]^T, bf16 in, f32 accum ----
// 256x256 block tile, BK=64, 8 waves (512 thr) each computing 128x64 (acc 8x4).
// Double-buffered LDS (128 KB) + counted vmcnt: per K-tile wait ONLY the current
// buffer's 8 loads (vmcnt(8)); next tile's loads stay in flight across barriers
// (T3+T4). Raw s_barrier, never __syncthreads (no vmcnt(0) drain in loop).
// T2 XOR swizzle both-sides (rule 21): linear LDS dest, inverse-swizzled global
// source (16B block ^= row&7), reads XOR the same bits.
template <int MODE>
__global__ __launch_bounds__(512, 2) void k_gemm_bt(
    const unsigned short* __restrict__ A, const unsigned short* __restrict__ Bt,
    int M, int N, int K,
    float* __restrict__ outF, const float* __restrict__ bias,
    unsigned short* __restrict__ Qd, unsigned short* __restrict__ Kd,
    unsigned short* __restrict__ Vt) {
  __shared__ __align__(16) unsigned short As[2][256 * 64];  // 64 KB
  __shared__ __align__(16) unsigned short Bs[2][256 * 64];  // 64 KB
  const int tid = threadIdx.x;
  const int lane = tid & 63, wid = tid >> 6;
  const int ln15 = lane & 15, lh = lane >> 4;
  const int wr = wid >> 2, wc = wid & 3;  // 2 M-groups x 4 N-groups
  const int m0 = blockIdx.x * 256, n0 = blockIdx.y * 256;
  f32x4 acc[8][4] = {};
  const int srow = lane >> 3;              // row within 8-row chunk
  const int sblk = ((lane & 7) ^ srow) * 8;  // inverse-swizzled 16B block
  const int swz = (ln15 & 7) << 3;
  const int nk = K >> 6;

  auto stage = [&](int kt, int s) {
    const int k0 = kt * 64;
#pragma unroll
    for (int c = 0; c < 4; ++c) {  // 32 chunks each for A and B; wave takes 4+4
      const int ch = wid * 4 + c;
      const int row = ch * 8 + srow;
      gload_lds16(A + (size_t)(m0 + row) * K + k0 + sblk, &As[s][ch * 512]);
      gload_lds16(Bt + (size_t)(n0 + row) * K + k0 + sblk, &Bs[s][ch * 512]);
    }
  };

  // prologue: two tiles in flight (16 loads outstanding per wave)
  stage(0, 0);
  stage(1, 1);

  for (int kt = 0; kt < nk; ++kt) {
    const int s = kt & 1;
    // wait current buffer's group only; newer group (kt+1, 8 loads) stays in flight
    if (kt < nk - 1) asm volatile("s_waitcnt vmcnt(8)" ::: "memory");
    else             asm volatile("s_waitcnt vmcnt(0)" ::: "memory");
    __builtin_amdgcn_s_barrier();
    __builtin_amdgcn_sched_barrier(0);
#pragma unroll
    for (int kk = 0; kk < 2; ++kk) {
      const int kc = kk * 32 + lh * 8;
      bf16x8 af[8], bfv[4];
#pragma unroll
      for (int mt = 0; mt < 8; ++mt)
        af[mt] = *reinterpret_cast<const bf16x8*>(
            &As[s][(wr * 128 + mt * 16 + ln15) * 64 + (kc ^ swz)]);
#pragma unroll
      for (int nt = 0; nt < 4; ++nt)
        bfv[nt] = *reinterpret_cast<const bf16x8*>(
            &Bs[s][(wc * 64 + nt * 16 + ln15) * 64 + (kc ^ swz)]);
      __builtin_amdgcn_s_setprio(1);
#pragma unroll
      for (int mt = 0; mt < 8; ++mt)
#pragma unroll
        for (int nt = 0; nt < 4; ++nt)
          acc[mt][nt] = __builtin_amdgcn_mfma_f32_16x16x32_bf16(af[mt], bfv[nt], acc[mt][nt], 0, 0, 0);
      __builtin_amdgcn_s_setprio(0);
    }
    __builtin_amdgcn_sched_barrier(0);
    __builtin_amdgcn_s_barrier();   // all waves done reading buf[s]
    __builtin_amdgcn_sched_barrier(0);
    if (kt + 2 < nk) stage(kt + 2, s);  // overwrite freed buffer; waited 2 iters later
  }

#pragma unroll
  for (int mt = 0; mt < 8; ++mt) {
#pragma unroll
    for (int nt = 0; nt < 4; ++nt) {
#pragma unroll
      for (int r = 0; r < 4; ++r) {
        const int m = m0 + wr * 128 + mt * 16 + lh * 4 + r;
        const int n = n0 + wc * 64 + nt * 16 + ln15;
        const float v = acc[mt][nt][r];
        if (MODE == 0) {
          outF[(size_t)m * N + n] = v + bias[n];
        } else {
          const int which = n / DMODEL;
          const int rr = n - which * DMODEL;
          const int h = rr >> 6, d = rr & 63;
          const int b = m >> 10, nr = m & 1023;
          const size_t bh = (size_t)(b * NHEAD + h);
          if (which == 0)      Qd[(bh * SEQ + nr) * HDIM + d] = f2bf(v * QSCALE);
          else if (which == 1) Kd[(bh * SEQ + nr) * HDIM + d] = f2bf(v);
          else                 Vt[(bh * HDIM + d) * SEQ + nr] = f2bf(v);
        }
      }
    }
  }
}

// ---- fused flash attention, swapped-QK^T in-register softmax ----
__global__ __launch_bounds__(256) void k_attn(
    const unsigned short* __restrict__ Qd, const unsigned short* __restrict__ Kd,
    const unsigned short* __restrict__ Vt, unsigned short* __restrict__ O) {
  __shared__ __align__(16) unsigned short Ks[64 * 64];      // [kpos][d], swizzled
  __shared__ __align__(16) unsigned short Vs[64 * 64];      // [d][kpos], swizzled
  __shared__ __align__(16) unsigned short Ps[4][16 * 72];   // per-wave P [q][kpos], stride 72
  const int tid = threadIdx.x;
  const int lane = tid & 63, w = tid >> 6;
  const int ln15 = lane & 15, lh = lane >> 4;
  const int bid = blockIdx.x;
  const int qb = bid & 15;
  const int h = (bid >> 4) % NHEAD;
  const int b = bid / (16 * NHEAD);
  const size_t bh = (size_t)(b * NHEAD + h);
  const unsigned short* Qbase = Qd + (bh * SEQ + (size_t)qb * 64 + w * 16) * HDIM;
  const unsigned short* Kbase = Kd + bh * SEQ * HDIM;
  const unsigned short* Vbase = Vt + bh * HDIM * SEQ;

  const int srow = lane >> 3;
  const int sblk = ((lane & 7) ^ srow) * 8;
  const int swz = (ln15 & 7) << 3;

  bf16x8 aq[2];
#pragma unroll
  for (int ch = 0; ch < 2; ++ch)
    aq[ch] = *reinterpret_cast<const bf16x8*>(Qbase + (size_t)ln15 * HDIM + ch * 32 + lh * 8);

  f32x4 acc[4] = {};
  float mr = -1e30f, lr = 0.f;

  for (int kb = 0; kb < SEQ / 64; ++kb) {
    const unsigned short* Kt = Kbase + (size_t)kb * 64 * HDIM;
#pragma unroll
    for (int c2 = 0; c2 < 2; ++c2) {
      const int c = w * 2 + c2;
      const int row = c * 8 + srow;
      gload_lds16(Kt + (size_t)row * 64 + sblk, &Ks[c * 512]);
      gload_lds16(Vbase + (size_t)row * SEQ + kb * 64 + sblk, &Vs[c * 512]);
    }
    __syncthreads();

    f32x4 s[4] = {};
    __builtin_amdgcn_s_setprio(1);
#pragma unroll
    for (int t = 0; t < 4; ++t) {
#pragma unroll
      for (int ch = 0; ch < 2; ++ch) {
        bf16x8 bk = *reinterpret_cast<const bf16x8*>(
            &Ks[(t * 16 + ln15) * 64 + ((ch * 32 + lh * 8) ^ swz)]);
        s[t] = __builtin_amdgcn_mfma_f32_16x16x32_bf16(bk, aq[ch], s[t], 0, 0, 0);
      }
    }
    __builtin_amdgcn_s_setprio(0);

    float bm;
    {
      const float a0 = fmaxf(fmaxf(s[0][0], s[0][1]), fmaxf(s[0][2], s[0][3]));
      const float a1 = fmaxf(fmaxf(s[1][0], s[1][1]), fmaxf(s[1][2], s[1][3]));
      const float a2 = fmaxf(fmaxf(s[2][0], s[2][1]), fmaxf(s[2][2], s[2][3]));
      const float a3 = fmaxf(fmaxf(s[3][0], s[3][1]), fmaxf(s[3][2], s[3][3]));
      bm = fmaxf(fmaxf(a0, a1), fmaxf(a2, a3));
    }
    bm = fmaxf(bm, __shfl_xor(bm, 16));
    bm = fmaxf(bm, __shfl_xor(bm, 32));
    const int grow = __any(bm > mr + 8.f);
    float al = 1.f;
    if (grow) {
      const float mn = fmaxf(mr, bm);
      al = __builtin_amdgcn_exp2f(mr - mn);
      mr = mn;
    }
#pragma unroll
    for (int t = 0; t < 4; ++t)
#pragma unroll
      for (int r = 0; r < 4; ++r) s[t][r] = __builtin_amdgcn_exp2f(s[t][r] - mr);
    float rs;
    {
      const float a0 = (s[0][0] + s[0][1]) + (s[0][2] + s[0][3]);
      const float a1 = (s[1][0] + s[1][1]) + (s[1][2] + s[1][3]);
      const float a2 = (s[2][0] + s[2][1]) + (s[2][2] + s[2][3]);
      const float a3 = (s[3][0] + s[3][1]) + (s[3][2] + s[3][3]);
      rs = (a0 + a1) + (a2 + a3);
    }
    rs += __shfl_xor(rs, 16);
    rs += __shfl_xor(rs, 32);
    lr = lr * al + rs;
    if (grow) {
      float alq[4];
#pragma unroll
      for (int r = 0; r < 4; ++r) alq[r] = __shfl(al, lh * 4 + r);
#pragma unroll
      for (int dt = 0; dt < 4; ++dt)
#pragma unroll
        for (int r = 0; r < 4; ++r) acc[dt][r] *= alq[r];
    }

#pragma unroll
    for (int t = 0; t < 4; ++t) {
      uint2 u;
      u.x = cvt_pk_bf16(s[t][0], s[t][1]);
      u.y = cvt_pk_bf16(s[t][2], s[t][3]);
      *reinterpret_cast<uint2*>(&Ps[w][ln15 * 72 + t * 16 + lh * 4]) = u;
    }

    bf16x8 ap[2];
#pragma unroll
    for (int ch = 0; ch < 2; ++ch)
      ap[ch] = *reinterpret_cast<const bf16x8*>(&Ps[w][ln15 * 72 + ch * 32 + lh * 8]);
    __builtin_amdgcn_s_setprio(1);
#pragma unroll
    for (int dt = 0; dt < 4; ++dt) {
#pragma unroll
      for (int ch = 0; ch < 2; ++ch) {
        bf16x8 bv = *reinterpret_cast<const bf16x8*>(
            &Vs[(dt * 16 + ln15) * 64 + ((ch * 32 + lh * 8) ^ swz)]);
        acc[dt] = __builtin_amdgcn_mfma_f32_16x16x32_bf16(ap[ch], bv, acc[dt], 0, 0, 0);
      }
    }
    __builtin_amdgcn_s_setprio(0);
    __syncthreads();
  }

  float lrq[4];
#pragma unroll
  for (int r = 0; r < 4; ++r) lrq[r] = 1.0f / __shfl(lr, lh * 4 + r);
  const int qrow = qb * 64 + w * 16 + lh * 4;
#pragma unroll
  for (int dt = 0; dt < 4; ++dt)
#pragma unroll
    for (int r = 0; r < 4; ++r)
      O[((size_t)b * SEQ + qrow + r) * DMODEL + h * 64 + dt * 16 + ln15] = f2bf(acc[dt][r] * lrq[r]);
}

extern "C" void kernel_launch(void* const* d_in, const int* in_sizes, int n_in,
                              void* d_out, int out_size, void* d_ws, size_t ws_size,
                              hipStream_t stream) {
  const float* x      = (const float*)d_in[0];
  const float* qkv_w  = (const float*)d_in[1];
  const float* proj_w = (const float*)d_in[2];
  const float* proj_b = (const float*)d_in[3];
  float* out = (float*)d_out;

  char* ws = (char*)d_ws;
  const size_t SZ_XB  = (size_t)MTOT * DMODEL * 2;   // x bf16; reused as attn-out bf16
  const size_t SZ_WQT = (size_t)NQKV * DMODEL * 2;
  const size_t SZ_WPT = (size_t)DMODEL * DMODEL * 2;
  const size_t SZ_QKV = (size_t)BB * NHEAD * SEQ * HDIM * 2;
  unsigned short* Xb  = (unsigned short*)ws;
  unsigned short* WqT = (unsigned short*)(ws + SZ_XB);
  unsigned short* WpT = (unsigned short*)(ws + SZ_XB + SZ_WQT);
  unsigned short* Qd  = (unsigned short*)(ws + SZ_XB + SZ_WQT + SZ_WPT);
  unsigned short* Kd  = (unsigned short*)(ws + SZ_XB + SZ_WQT + SZ_WPT + SZ_QKV);
  unsigned short* Vt  = (unsigned short*)(ws + SZ_XB + SZ_WQT + SZ_WPT + 2 * SZ_QKV);
  if (ws_size < SZ_XB + SZ_WQT + SZ_WPT + 3 * SZ_QKV) return;

  // 1) x -> bf16
  k_cvt_bf16<<<2048, 256, 0, stream>>>((const float4*)x, (ushort4*)Xb, MTOT * DMODEL / 4);
  // 2) weight transposes (f32 -> bf16, B^T layout)
  k_transpose_bf16<<<dim3(NQKV / 32, DMODEL / 32), 256, 0, stream>>>(qkv_w, WqT, DMODEL, NQKV);
  k_transpose_bf16<<<dim3(DMODEL / 32, DMODEL / 32), 256, 0, stream>>>(proj_w, WpT, DMODEL, DMODEL);
  // 3) QKV projection -> per-head Q (pre-scaled), K, V^T.
  //    x-major grid: consecutive blocks share the B n-panel; blocks with equal
  //    m-index land on the same XCD (ids differ by 64 = 0 mod 8) -> A panel L2 reuse.
  k_gemm_bt<1><<<dim3(MTOT / 256, NQKV / 256), 512, 0, stream>>>(
      Xb, WqT, MTOT, NQKV, DMODEL, nullptr, nullptr, Qd, Kd, Vt);
  // 4) fused attention -> Oattn (reuses Xb region)
  k_attn<<<BB * NHEAD * (SEQ / 64), 256, 0, stream>>>(Qd, Kd, Vt, Xb);
  // 5) output projection + bias -> f32 out
  k_gemm_bt<0><<<dim3(MTOT / 256, DMODEL / 256), 512, 0, stream>>>(
      Xb, WpT, MTOT, DMODEL, DMODEL, out, proj_b, nullptr, nullptr, nullptr);
}